// Round 3
// baseline (242.744 us; speedup 1.0000x reference)
//
#include <hip/hip_runtime.h>
#include <hip/hip_cooperative_groups.h>
#include <stdint.h>

namespace cg = cooperative_groups;

#define N_NODES 524288
#define BLOCK 128
#define NUM_BLOCKS 4096
#define MAX_KV 64
#define GRAPH_WEIGHT 0.3f

#define GRID_BLOCKS 512   // 8 node-blocks per workgroup; 2 blocks/CU -> co-residency safe
#define THREADS 256

// ws float-index layout (per-node-block partials; no atomics anywhere)
#define WS_SUMP 0            // [4096] sum of keep*p
#define WS_CNTK 4096         // [4096] keep count
#define WS_QCNT 8192         // [4096] uncertain count
#define WS_BCEP 12288        // [4096] sum(bce*sup)
#define WS_SUPP 16384        // [4096] sum(sup)
#define WS_GNUM 20480        // [4096] blk_loss*valid
#define WS_GCNT 24576        // [4096] valid

__device__ __forceinline__ float sigmoidf_(float x) { return 1.f / (1.f + expf(-x)); }
__device__ __forceinline__ float bcef_(float x, float tg) {
    return fmaxf(x, 0.f) + log1pf(expf(-fabsf(x))) - tg * x;   // stable softplus(x)-t*x
}

// Mask-layout detection: every block scans the same first 1024 bytes of sup.
// Byte-packed bools (p=0.2) give a u32 word >1 with P(miss)~0.512^256~=3e-75;
// int32 0/1 arrays can never produce a word >1. In-bounds for both layouts.
__device__ __forceinline__ int detect_byteflag(const void* sup, int t, int* sh_flag) {
    if (t == 0) *sh_flag = 0;
    __syncthreads();
    unsigned int a = ((const unsigned int*)sup)[t & 255];
    if (a > 1u) *sh_flag = 1;   // benign same-value race
    __syncthreads();
    return *sh_flag;
}

__global__ void __launch_bounds__(THREADS)
fused_coop(const float* __restrict__ logits, const float* __restrict__ targets,
           const void* __restrict__ sup, const void* __restrict__ ign,
           const int* __restrict__ kvi, const int* __restrict__ kvn,
           float* __restrict__ ws, float* __restrict__ out) {
    cg::grid_group grid = cg::this_grid();
    const int t = threadIdx.x;
    const int wave = t >> 6, lane = t & 63;
    __shared__ int sh_flag;
    const int bf = detect_byteflag(sup, t, &sh_flag);

    // ---- Phase A: per-node-block stats. 32 lanes per node-block, 4 nodes/lane (float4).
    {
        const int sub = t >> 5;                       // 0..7
        const int nb  = (blockIdx.x << 3) + sub;
        const int l32 = t & 31;
        const int base = (nb << 7) + (l32 << 2);
        const float4 x4  = *(const float4*)(logits  + base);
        const float4 tg4 = *(const float4*)(targets + base);
        bool s[4], g[4];
        if (bf) {
            unsigned sw = *(const unsigned*)((const uint8_t*)sup + base);
            unsigned gw = *(const unsigned*)((const uint8_t*)ign + base);
            #pragma unroll
            for (int k = 0; k < 4; ++k) {
                s[k] = ((sw >> (8 * k)) & 0xffu) != 0;
                g[k] = ((gw >> (8 * k)) & 0xffu) != 0;
            }
        } else {
            int4 sv = *(const int4*)((const int*)sup + base);
            int4 gv = *(const int4*)((const int*)ign + base);
            s[0] = sv.x; s[1] = sv.y; s[2] = sv.z; s[3] = sv.w;
            g[0] = gv.x; g[1] = gv.y; g[2] = gv.z; g[3] = gv.w;
        }
        const float x[4]  = {x4.x, x4.y, x4.z, x4.w};
        const float tg[4] = {tg4.x, tg4.y, tg4.z, tg4.w};
        float v0 = 0.f, v1 = 0.f, v2 = 0.f, v3 = 0.f, v4 = 0.f;
        #pragma unroll
        for (int k = 0; k < 4; ++k) {
            float p = sigmoidf_(x[k]);
            if (!g[k]) { v0 += p; v1 += 1.f; if (!s[k]) v2 += 1.f; }
            if (s[k])  { v3 += bcef_(x[k], tg[k]); v4 += 1.f; }
        }
        #pragma unroll
        for (int off = 16; off > 0; off >>= 1) {
            v0 += __shfl_down(v0, off, 32);
            v1 += __shfl_down(v1, off, 32);
            v2 += __shfl_down(v2, off, 32);
            v3 += __shfl_down(v3, off, 32);
            v4 += __shfl_down(v4, off, 32);
        }
        if (l32 == 0) {
            ws[WS_SUMP + nb] = v0;
            ws[WS_CNTK + nb] = v1;
            ws[WS_QCNT + nb] = v2;
            ws[WS_BCEP + nb] = v3;
            ws[WS_SUPP + nb] = v4;
        }
    }
    __threadfence();
    grid.sync();

    // ---- Phase B: one wave per node-block (2 passes of 4 waves over this block's 8).
    #pragma unroll
    for (int pass = 0; pass < 2; ++pass) {
        const int nb = (blockIdx.x << 3) + (pass << 2) + wave;
        const int num = kvn[nb];
        float ns = 0.f, nc = 0.f;
        if (lane < num) {
            int j = kvi[(nb << 6) + lane];
            ns = ws[WS_SUMP + j];
            nc = ws[WS_CNTK + j];
        }
        #pragma unroll
        for (int off = 32; off > 0; off >>= 1) {
            ns += __shfl_down(ns, off);
            nc += __shfl_down(nc, off);
        }
        ns = __shfl(ns, 0); nc = __shfl(nc, 0);
        const float nmean = ns / fmaxf(nc, 1.f);
        const int base = (nb << 7) + (lane << 1);
        const float2 x2 = *(const float2*)(logits + base);
        bool s0, s1, g0, g1;
        if (bf) {
            const uint8_t* sb = (const uint8_t*)sup;
            const uint8_t* gb = (const uint8_t*)ign;
            s0 = sb[base]; s1 = sb[base + 1];
            g0 = gb[base]; g1 = gb[base + 1];
        } else {
            const int* si = (const int*)sup;
            const int* gi = (const int*)ign;
            s0 = si[base]; s1 = si[base + 1];
            g0 = gi[base]; g1 = gi[base + 1];
        }
        float d0 = sigmoidf_(x2.x) - nmean;
        float d1 = sigmoidf_(x2.y) - nmean;
        float v = ((!g0 && !s0) ? d0 * d0 : 0.f) + ((!g1 && !s1) ? d1 * d1 : 0.f);
        #pragma unroll
        for (int off = 32; off > 0; off >>= 1) v += __shfl_down(v, off);
        if (lane == 0) {
            float qc = ws[WS_QCNT + nb];
            bool valid = (qc > 0.f) && (nc > 0.f);
            ws[WS_GNUM + nb] = valid ? v / fmaxf(qc, 1.f) : 0.f;
            ws[WS_GCNT + nb] = valid ? 1.f : 0.f;
        }
    }
    __threadfence();
    grid.sync();

    // ---- Phase C: block 0 reduces the 4096-entry partial arrays.
    if (blockIdx.x == 0) {
        float bce = 0.f, scnt = 0.f, gnum = 0.f, gcnt = 0.f;
        for (int b = t; b < NUM_BLOCKS; b += THREADS) {
            bce  += ws[WS_BCEP + b];
            scnt += ws[WS_SUPP + b];
            gnum += ws[WS_GNUM + b];
            gcnt += ws[WS_GCNT + b];
        }
        #pragma unroll
        for (int off = 32; off > 0; off >>= 1) {
            bce  += __shfl_down(bce, off);
            scnt += __shfl_down(scnt, off);
            gnum += __shfl_down(gnum, off);
            gcnt += __shfl_down(gcnt, off);
        }
        __shared__ float sh[4][4];
        if (lane == 0) { sh[wave][0] = bce; sh[wave][1] = scnt; sh[wave][2] = gnum; sh[wave][3] = gcnt; }
        __syncthreads();
        if (t == 0) {
            float bs = sh[0][0] + sh[1][0] + sh[2][0] + sh[3][0];
            float sc = sh[0][1] + sh[1][1] + sh[2][1] + sh[3][1];
            float gn = sh[0][2] + sh[1][2] + sh[2][2] + sh[3][2];
            float gc = sh[0][3] + sh[1][3] + sh[2][3] + sh[3][3];
            float loss_sup = (sc > 0.f) ? bs / fmaxf(sc, 1.f) : 0.f;
            out[0] = loss_sup + GRAPH_WEIGHT * (gn / fmaxf(gc, 1.f));
        }
    }
}

// ---------------- fallback path (round-2 kernels, known-correct) ----------------
__global__ void __launch_bounds__(BLOCK)
k1_per_block(const float* __restrict__ logits, const float* __restrict__ targets,
             const void* __restrict__ sup, const void* __restrict__ ign,
             float* __restrict__ ws) {
    const int b = blockIdx.x, t = threadIdx.x;
    const int i = b * BLOCK + t;
    __shared__ int sh_flag;
    const int bf = detect_byteflag(sup, t, &sh_flag);
    float x = logits[i], tg = targets[i];
    bool s = bf ? (((const uint8_t*)sup)[i] != 0) : (((const int*)sup)[i] != 0);
    bool g = bf ? (((const uint8_t*)ign)[i] != 0) : (((const int*)ign)[i] != 0);
    float bce = bcef_(x, tg);
    float p = sigmoidf_(x);
    float v0 = g ? 0.f : p, v1 = g ? 0.f : 1.f, v2 = (!g && !s) ? 1.f : 0.f;
    float v3 = s ? bce : 0.f, v4 = s ? 1.f : 0.f;
    for (int off = 32; off > 0; off >>= 1) {
        v0 += __shfl_down(v0, off); v1 += __shfl_down(v1, off); v2 += __shfl_down(v2, off);
        v3 += __shfl_down(v3, off); v4 += __shfl_down(v4, off);
    }
    __shared__ float sh[2][5];
    if ((t & 63) == 0) { int w = t >> 6; sh[w][0]=v0; sh[w][1]=v1; sh[w][2]=v2; sh[w][3]=v3; sh[w][4]=v4; }
    __syncthreads();
    if (t == 0) {
        ws[WS_SUMP + b] = sh[0][0] + sh[1][0];
        ws[WS_CNTK + b] = sh[0][1] + sh[1][1];
        ws[WS_QCNT + b] = sh[0][2] + sh[1][2];
        ws[WS_BCEP + b] = sh[0][3] + sh[1][3];
        ws[WS_SUPP + b] = sh[0][4] + sh[1][4];
    }
}

__global__ void __launch_bounds__(BLOCK)
k2_graph(const float* __restrict__ logits,
         const void* __restrict__ sup, const void* __restrict__ ign,
         const int* __restrict__ kvi, const int* __restrict__ kvn,
         float* __restrict__ ws) {
    const int b = blockIdx.x, t = threadIdx.x;
    __shared__ int sh_flag;
    const int bf = detect_byteflag(sup, t, &sh_flag);
    __shared__ float sh_nmean, sh_ncnt;
    if (t < 64) {
        float ns = 0.f, nc = 0.f;
        int num = kvn[b];
        if (t < num) { int j = kvi[b * MAX_KV + t]; ns = ws[WS_SUMP + j]; nc = ws[WS_CNTK + j]; }
        for (int off = 32; off > 0; off >>= 1) { ns += __shfl_down(ns, off); nc += __shfl_down(nc, off); }
        if (t == 0) { sh_ncnt = nc; sh_nmean = ns / fmaxf(nc, 1.f); }
    }
    __syncthreads();
    const float nmean = sh_nmean, ncnt = sh_ncnt;
    const int i = b * BLOCK + t;
    float x = logits[i];
    bool s = bf ? (((const uint8_t*)sup)[i] != 0) : (((const int*)sup)[i] != 0);
    bool g = bf ? (((const uint8_t*)ign)[i] != 0) : (((const int*)ign)[i] != 0);
    float d = sigmoidf_(x) - nmean;
    float v = (!g && !s) ? d * d : 0.f;
    for (int off = 32; off > 0; off >>= 1) v += __shfl_down(v, off);
    __shared__ float shv[2];
    if ((t & 63) == 0) shv[t >> 6] = v;
    __syncthreads();
    if (t == 0) {
        float vs = shv[0] + shv[1];
        float qc = ws[WS_QCNT + b];
        bool valid = (qc > 0.f) && (ncnt > 0.f);
        ws[WS_GNUM + b] = valid ? vs / fmaxf(qc, 1.f) : 0.f;
        ws[WS_GCNT + b] = valid ? 1.f : 0.f;
    }
}

__global__ void __launch_bounds__(256)
k3_final(const float* __restrict__ ws, float* __restrict__ out) {
    const int t = threadIdx.x;
    float bce = 0.f, scnt = 0.f, gnum = 0.f, gcnt = 0.f;
    for (int b = t; b < NUM_BLOCKS; b += 256) {
        bce += ws[WS_BCEP + b]; scnt += ws[WS_SUPP + b];
        gnum += ws[WS_GNUM + b]; gcnt += ws[WS_GCNT + b];
    }
    for (int off = 32; off > 0; off >>= 1) {
        bce += __shfl_down(bce, off); scnt += __shfl_down(scnt, off);
        gnum += __shfl_down(gnum, off); gcnt += __shfl_down(gcnt, off);
    }
    __shared__ float sh[4][4];
    if ((t & 63) == 0) { int w = t >> 6; sh[w][0]=bce; sh[w][1]=scnt; sh[w][2]=gnum; sh[w][3]=gcnt; }
    __syncthreads();
    if (t == 0) {
        float bs = sh[0][0]+sh[1][0]+sh[2][0]+sh[3][0];
        float sc = sh[0][1]+sh[1][1]+sh[2][1]+sh[3][1];
        float gn = sh[0][2]+sh[1][2]+sh[2][2]+sh[3][2];
        float gc = sh[0][3]+sh[1][3]+sh[2][3]+sh[3][3];
        float loss_sup = (sc > 0.f) ? bs / fmaxf(sc, 1.f) : 0.f;
        out[0] = loss_sup + GRAPH_WEIGHT * (gn / fmaxf(gc, 1.f));
    }
}

extern "C" void kernel_launch(void* const* d_in, const int* in_sizes, int n_in,
                              void* d_out, int out_size, void* d_ws, size_t ws_size,
                              hipStream_t stream) {
    const float* logits  = (const float*)d_in[0];
    const float* targets = (const float*)d_in[1];
    const void*  sup     = d_in[2];
    const void*  ign     = d_in[3];
    const int*   kvi     = (const int*)d_in[4];
    const int*   kvn     = (const int*)d_in[5];
    float* out = (float*)d_out;
    float* ws  = (float*)d_ws;

    void* args[] = {(void*)&logits, (void*)&targets, (void*)&sup, (void*)&ign,
                    (void*)&kvi, (void*)&kvn, (void*)&ws, (void*)&out};
    hipError_t err = hipLaunchCooperativeKernel((void*)fused_coop,
                                                dim3(GRID_BLOCKS), dim3(THREADS),
                                                args, 0, stream);
    if (err != hipSuccess) {
        (void)hipGetLastError();  // clear and fall back to the 3-kernel path
        k1_per_block<<<NUM_BLOCKS, BLOCK, 0, stream>>>(logits, targets, sup, ign, ws);
        k2_graph<<<NUM_BLOCKS, BLOCK, 0, stream>>>(logits, sup, ign, kvi, kvn, ws);
        k3_final<<<1, 256, 0, stream>>>(ws, out);
    }
}

// Round 4
// 83.705 us; speedup vs baseline: 2.9000x; 2.9000x over previous
//
#include <hip/hip_runtime.h>
#include <stdint.h>

#define N_NODES 524288
#define BLOCK 128
#define NUM_BLOCKS 4096
#define MAX_KV 64
#define GRAPH_WEIGHT 0.3f

// ws float-index layout (per-node-block partials; no atomics anywhere)
#define WS_SUMP 0            // [4096] sum of keep*p
#define WS_CNTK 4096         // [4096] keep count
#define WS_QCNT 8192         // [4096] uncertain count
#define WS_BCEP 12288        // [4096] sum(bce*sup)
#define WS_SUPP 16384        // [4096] sum(sup)
#define WS_GNUM 20480        // [4096] blk_loss*valid
#define WS_GCNT 24576        // [4096] valid

__device__ __forceinline__ float sigmoidf_(float x) { return 1.f / (1.f + expf(-x)); }
__device__ __forceinline__ float bcef_(float x, float tg) {
    return fmaxf(x, 0.f) + log1pf(expf(-fabsf(x))) - tg * x;   // stable softplus(x)-t*x
}

// Mask-layout detection: every block scans the same first 1024 bytes of sup.
// Byte-packed bools (p=0.2) give a u32 word >1 with P(miss)~0.512^256~=3e-75;
// int32 0/1 arrays can never produce a word >1. In-bounds for both layouts,
// and the 1 KB region is L2-broadcast across blocks.
__device__ __forceinline__ int detect_byteflag(const void* sup, int t, int* sh_flag) {
    if (t == 0) *sh_flag = 0;
    __syncthreads();
    unsigned int a = ((const unsigned int*)sup)[t & 255];
    if (a > 1u) *sh_flag = 1;   // benign same-value race
    __syncthreads();
    return *sh_flag;
}

// ---- k1: per-node-block stats. 512 blocks x 256 thr; 32 lanes per node-block,
// 4 nodes/lane via float4/int4. Pure width-32 shuffle reduce, no LDS tree.
__global__ void __launch_bounds__(256)
k1_stats(const float* __restrict__ logits, const float* __restrict__ targets,
         const void* __restrict__ sup, const void* __restrict__ ign,
         float* __restrict__ ws) {
    const int t = threadIdx.x;
    __shared__ int sh_flag;
    const int bf = detect_byteflag(sup, t, &sh_flag);

    const int sub = t >> 5;                        // 0..7: node-block within this wg
    const int nb  = (blockIdx.x << 3) + sub;       // node-block id
    const int l32 = t & 31;
    const int base = (nb << 7) + (l32 << 2);       // 4 nodes per lane

    const float4 x4  = *(const float4*)(logits  + base);
    const float4 tg4 = *(const float4*)(targets + base);
    bool s[4], g[4];
    if (bf) {
        unsigned sw = *(const unsigned*)((const uint8_t*)sup + base);
        unsigned gw = *(const unsigned*)((const uint8_t*)ign + base);
        #pragma unroll
        for (int k = 0; k < 4; ++k) {
            s[k] = ((sw >> (8 * k)) & 0xffu) != 0;
            g[k] = ((gw >> (8 * k)) & 0xffu) != 0;
        }
    } else {
        int4 sv = *(const int4*)((const int*)sup + base);
        int4 gv = *(const int4*)((const int*)ign + base);
        s[0] = sv.x != 0; s[1] = sv.y != 0; s[2] = sv.z != 0; s[3] = sv.w != 0;
        g[0] = gv.x != 0; g[1] = gv.y != 0; g[2] = gv.z != 0; g[3] = gv.w != 0;
    }
    const float x[4]  = {x4.x, x4.y, x4.z, x4.w};
    const float tg[4] = {tg4.x, tg4.y, tg4.z, tg4.w};
    float v0 = 0.f, v1 = 0.f, v2 = 0.f, v3 = 0.f, v4 = 0.f;
    #pragma unroll
    for (int k = 0; k < 4; ++k) {
        float p = sigmoidf_(x[k]);
        if (!g[k]) { v0 += p; v1 += 1.f; if (!s[k]) v2 += 1.f; }
        if (s[k])  { v3 += bcef_(x[k], tg[k]); v4 += 1.f; }
    }
    #pragma unroll
    for (int off = 16; off > 0; off >>= 1) {
        v0 += __shfl_down(v0, off, 32);
        v1 += __shfl_down(v1, off, 32);
        v2 += __shfl_down(v2, off, 32);
        v3 += __shfl_down(v3, off, 32);
        v4 += __shfl_down(v4, off, 32);
    }
    if (l32 == 0) {
        ws[WS_SUMP + nb] = v0;
        ws[WS_CNTK + nb] = v1;
        ws[WS_QCNT + nb] = v2;
        ws[WS_BCEP + nb] = v3;
        ws[WS_SUPP + nb] = v4;
    }
}

// ---- k2: graph term. 1024 blocks x 256 thr; one wave per node-block.
__global__ void __launch_bounds__(256)
k2_graph(const float* __restrict__ logits,
         const void* __restrict__ sup, const void* __restrict__ ign,
         const int* __restrict__ kvi, const int* __restrict__ kvn,
         float* __restrict__ ws) {
    const int t = threadIdx.x;
    const int wave = t >> 6, lane = t & 63;
    __shared__ int sh_flag;
    const int bf = detect_byteflag(sup, t, &sh_flag);

    const int nb = (blockIdx.x << 2) + wave;       // node-block id
    const int num = kvn[nb];
    float ns = 0.f, nc = 0.f;
    if (lane < num) {
        int j = kvi[(nb << 6) + lane];
        ns = ws[WS_SUMP + j];
        nc = ws[WS_CNTK + j];
    }
    #pragma unroll
    for (int off = 32; off > 0; off >>= 1) {
        ns += __shfl_down(ns, off);
        nc += __shfl_down(nc, off);
    }
    ns = __shfl(ns, 0); nc = __shfl(nc, 0);
    const float nmean = ns / fmaxf(nc, 1.f);

    const int base = (nb << 7) + (lane << 1);      // 2 nodes per lane
    const float2 x2 = *(const float2*)(logits + base);
    bool s0, s1, g0, g1;
    if (bf) {
        const uint8_t* sb = (const uint8_t*)sup;
        const uint8_t* gb = (const uint8_t*)ign;
        s0 = sb[base] != 0; s1 = sb[base + 1] != 0;
        g0 = gb[base] != 0; g1 = gb[base + 1] != 0;
    } else {
        const int* si = (const int*)sup;
        const int* gi = (const int*)ign;
        s0 = si[base] != 0; s1 = si[base + 1] != 0;
        g0 = gi[base] != 0; g1 = gi[base + 1] != 0;
    }
    float d0 = sigmoidf_(x2.x) - nmean;
    float d1 = sigmoidf_(x2.y) - nmean;
    float v = ((!g0 && !s0) ? d0 * d0 : 0.f) + ((!g1 && !s1) ? d1 * d1 : 0.f);
    #pragma unroll
    for (int off = 32; off > 0; off >>= 1) v += __shfl_down(v, off);
    if (lane == 0) {
        float qc = ws[WS_QCNT + nb];
        bool valid = (qc > 0.f) && (nc > 0.f);
        ws[WS_GNUM + nb] = valid ? v / fmaxf(qc, 1.f) : 0.f;
        ws[WS_GCNT + nb] = valid ? 1.f : 0.f;
    }
}

// ---- k3: single-block final reduce of the 4096-entry partial arrays.
__global__ void __launch_bounds__(256)
k3_final(const float* __restrict__ ws, float* __restrict__ out) {
    const int t = threadIdx.x;
    float bce = 0.f, scnt = 0.f, gnum = 0.f, gcnt = 0.f;
    for (int b = t; b < NUM_BLOCKS; b += 256) {
        bce  += ws[WS_BCEP + b];
        scnt += ws[WS_SUPP + b];
        gnum += ws[WS_GNUM + b];
        gcnt += ws[WS_GCNT + b];
    }
    #pragma unroll
    for (int off = 32; off > 0; off >>= 1) {
        bce  += __shfl_down(bce, off);
        scnt += __shfl_down(scnt, off);
        gnum += __shfl_down(gnum, off);
        gcnt += __shfl_down(gcnt, off);
    }
    __shared__ float sh[4][4];
    if ((t & 63) == 0) {
        int w = t >> 6;
        sh[w][0] = bce; sh[w][1] = scnt; sh[w][2] = gnum; sh[w][3] = gcnt;
    }
    __syncthreads();
    if (t == 0) {
        float bs = sh[0][0] + sh[1][0] + sh[2][0] + sh[3][0];
        float sc = sh[0][1] + sh[1][1] + sh[2][1] + sh[3][1];
        float gn = sh[0][2] + sh[1][2] + sh[2][2] + sh[3][2];
        float gc = sh[0][3] + sh[1][3] + sh[2][3] + sh[3][3];
        float loss_sup = (sc > 0.f) ? bs / fmaxf(sc, 1.f) : 0.f;
        out[0] = loss_sup + GRAPH_WEIGHT * (gn / fmaxf(gc, 1.f));
    }
}

extern "C" void kernel_launch(void* const* d_in, const int* in_sizes, int n_in,
                              void* d_out, int out_size, void* d_ws, size_t ws_size,
                              hipStream_t stream) {
    const float* logits  = (const float*)d_in[0];
    const float* targets = (const float*)d_in[1];
    const void*  sup     = d_in[2];
    const void*  ign     = d_in[3];
    const int*   kvi     = (const int*)d_in[4];
    const int*   kvn     = (const int*)d_in[5];
    float* out = (float*)d_out;
    float* ws  = (float*)d_ws;

    k1_stats<<<NUM_BLOCKS / 8, 256, 0, stream>>>(logits, targets, sup, ign, ws);
    k2_graph<<<NUM_BLOCKS / 4, 256, 0, stream>>>(logits, sup, ign, kvi, kvn, ws);
    k3_final<<<1, 256, 0, stream>>>(ws, out);
}